// Round 7
// baseline (225.195 us; speedup 1.0000x reference)
//
#include <hip/hip_runtime.h>
#include <hip/hip_bf16.h>
#include <stdint.h>

// ---------------- constants ----------------
constexpr int Nn = 8192;
constexpr int Dd = 1024;
constexpr float kAlpha = 0.1f;
constexpr float kEps = 1e-7f;
constexpr float kInf = 3.0e38f;

constexpr int BM = 256, BN = 256;
constexpr int NB = Nn / BM;               // 32 row/col blocks
constexpr int NPAIR = NB * (NB + 1) / 2;  // 528 upper-triangle tile pairs
constexpr int NH = Dd / 32;               // 32 K-halves (each 32 wide)

using bfx8 = __attribute__((ext_vector_type(8))) __bf16;   // MFMA A/B frag
using f32x4 = __attribute__((ext_vector_type(4))) float;   // MFMA C/D frag

__device__ __forceinline__ unsigned short f2bf(float f) {
  union { float f; unsigned int u; } v; v.f = f;
  unsigned int u = v.u;
  u = u + 0x7fffu + ((u >> 16) & 1u);  // RNE
  return (unsigned short)(u >> 16);
}

__device__ __forceinline__ void min2_insert(float& m1, float& m2, float x) {
  const float lo = fminf(m1, x);
  const float hi = fmaxf(m1, x);
  m1 = lo;
  m2 = fminf(m2, hi);
}

__device__ __forceinline__ void min2_merge(float& m1, float& m2, float o1, float o2) {
  m2 = fminf(fminf(m2, o2), fmaxf(m1, o1));
  m1 = fminf(m1, o1);
}

// ---------------- prep: fp32 -> bf16 + row sq-norms ----------------
__global__ __launch_bounds__(256) void prep_kernel(const float* __restrict__ H,
                                                   unsigned short* __restrict__ Hb,
                                                   float* __restrict__ xn) {
  const int wave = threadIdx.x >> 6;
  const int lane = threadIdx.x & 63;
  const int row = blockIdx.x * 4 + wave;
  const float4* src = (const float4*)(H + (size_t)row * Dd);
  ushort4* dst = (ushort4*)(Hb + (size_t)row * Dd);
  float acc = 0.f;
#pragma unroll
  for (int i = 0; i < 4; ++i) {
    float4 v = src[lane + 64 * i];
    acc = fmaf(v.x, v.x, acc);
    acc = fmaf(v.y, v.y, acc);
    acc = fmaf(v.z, v.z, acc);
    acc = fmaf(v.w, v.w, acc);
    ushort4 o;
    o.x = f2bf(v.x); o.y = f2bf(v.y); o.z = f2bf(v.z); o.w = f2bf(v.w);
    dst[lane + 64 * i] = o;
  }
#pragma unroll
  for (int off = 32; off; off >>= 1) acc += __shfl_xor(acc, off, 64);
  if (lane == 0) xn[row] = acc;
}

// ---------------- main: 8-phase 256x256 fused GEMM + triplet reductions ------
// m201-template port. Per K-half (32 wide), two phases:
//   Ph1: ds_read a[0..3],b[0..3] (8xb128) + stage A-half(h+3) (2 gload_lds)
//        -> barrier -> lgkmcnt(0) -> setprio(1) 16 MFMA setprio(0) -> barrier
//   Ph2: ds_read a[4..7] (4xb128) + stage B-half(h+3) (2 gload_lds)
//        + counted vmcnt (8 steady / 4 / 0 at tail; NEVER 0 mid-loop)
//        -> barrier -> lgkmcnt(0) -> setprio(1) 16 MFMA setprio(0) -> barrier
// LDS: 4 half-slots x (A 16KB + B 16KB) = 128 KB; stage-ahead 3 halves.
// vmcnt ledger: 4 loads/half/wave; at the wait point halves h+2,h+3 may be
// outstanding (8) -> vmcnt(8) guarantees half h+1 landed before its Ph1 reads.
// Both-sides XOR swizzle within 64B LDS rows (verified conflict-free r1-r6);
// bijective XCD swizzle (528 % 8 == 0).
__global__ __launch_bounds__(512, 2) void triplet_main(
    const unsigned short* __restrict__ Hb, const float* __restrict__ xn,
    const int* __restrict__ lab, float* __restrict__ wsMax,
    float* __restrict__ wsM1, float* __restrict__ wsM2) {
  __shared__ __align__(16) unsigned char smem[131072];  // 4 x (16KB A + 16KB B)

  const int tid = threadIdx.x;
  const int wave = tid >> 6;   // 0..7
  const int lane = tid & 63;
  const int quad = lane >> 4;
  const int l15 = lane & 15;
  const int wm = wave & 1;     // row group: 128 rows
  const int wn = wave >> 1;    // col group: 64 cols (4 groups)

  // XCD-aware swizzle: 8 XCDs, contiguous chunk of 66 pairs per XCD.
  int bid = (int)blockIdx.x;
  bid = (bid & 7) * (NPAIR / 8) + (bid >> 3);

  // decode pair index -> (I, J), I <= J
  int b = bid, I = 0;
  while (b >= NB - I) { b -= NB - I; ++I; }
  const int J = I + b;
  const bool diag = (I == J);

  const int rowBase = I * BM;
  const int colBase = J * BN;

  // staging map: wave w stages rows [ro*128 + w*16, +16); lane -> (row=lane>>2,
  // 16B slot=lane&3). Slot XOR-swizzled via the GLOBAL source (LDS dest linear,
  // required by global_load_lds); key = ((row&15)>>1)&3 = (lane>>3)&3.
  const int sRow = lane >> 2;
  const int sCol = ((lane & 3) ^ ((lane >> 3) & 3)) * 8;   // short offset
  const int swq = quad ^ ((l15 >> 1) & 3);                 // read-side swizzle

  f32x4 acc[8][4];
#pragma unroll
  for (int m = 0; m < 8; ++m)
#pragma unroll
    for (int n = 0; n < 4; ++n) acc[m][n] = {0.f, 0.f, 0.f, 0.f};

  auto stageA = [&](int slot, int hh) {
    unsigned short* base = (unsigned short*)(smem + slot * 32768);
#pragma unroll
    for (int ro = 0; ro < 2; ++ro) {
      const int row0 = ro * 128 + wave * 16;
      const unsigned short* g =
          Hb + (size_t)(rowBase + row0 + sRow) * Dd + hh * 32 + sCol;
      __builtin_amdgcn_global_load_lds(
          (const __attribute__((address_space(1))) void*)g,
          (__attribute__((address_space(3))) void*)&base[row0 * 32], 16, 0, 0);
    }
  };
  auto stageB = [&](int slot, int hh) {
    unsigned short* base = (unsigned short*)(smem + slot * 32768 + 16384);
#pragma unroll
    for (int ro = 0; ro < 2; ++ro) {
      const int row0 = ro * 128 + wave * 16;
      const unsigned short* g =
          Hb + (size_t)(colBase + row0 + sRow) * Dd + hh * 32 + sCol;
      __builtin_amdgcn_global_load_lds(
          (const __attribute__((address_space(1))) void*)g,
          (__attribute__((address_space(3))) void*)&base[row0 * 32], 16, 0, 0);
    }
  };

  // prologue: stage halves 0,1,2; wait own half-0 loads (8 newer allowed).
  stageA(0, 0); stageB(0, 0);
  stageA(1, 1); stageB(1, 1);
  stageA(2, 2); stageB(2, 2);
  asm volatile("s_waitcnt vmcnt(8)" ::: "memory");
  __builtin_amdgcn_s_barrier();

  for (int h = 0; h < NH; ++h) {
    const int slot = h & 3;
    const int nslot = (h + 3) & 3;
    const unsigned short* Ah = (const unsigned short*)(smem + slot * 32768);
    const unsigned short* Bh = (const unsigned short*)(smem + slot * 32768 + 16384);

    // ---- Phase 1: reads + A-stage, barrier, 16 MFMA (m0..3) ----
    bfx8 aF[4], bF[4];
#pragma unroll
    for (int m = 0; m < 4; ++m)
      aF[m] = *(const bfx8*)&Ah[(wm * 128 + m * 16 + l15) * 32 + swq * 8];
#pragma unroll
    for (int n = 0; n < 4; ++n)
      bF[n] = *(const bfx8*)&Bh[(wn * 64 + n * 16 + l15) * 32 + swq * 8];
    if (h + 3 < NH) stageA(nslot, h + 3);

    __builtin_amdgcn_s_barrier();
    asm volatile("s_waitcnt lgkmcnt(0)" ::: "memory");
    __builtin_amdgcn_s_setprio(1);
#pragma unroll
    for (int m = 0; m < 4; ++m)
#pragma unroll
      for (int n = 0; n < 4; ++n)
        acc[m][n] = __builtin_amdgcn_mfma_f32_16x16x32_bf16(aF[m], bF[n], acc[m][n], 0, 0, 0);
    __builtin_amdgcn_s_setprio(0);
    __builtin_amdgcn_s_barrier();

    // ---- Phase 2: reads + B-stage + counted vmcnt, barrier, 16 MFMA (m4..7) ----
    bfx8 aS[4];
#pragma unroll
    for (int m = 0; m < 4; ++m)
      aS[m] = *(const bfx8*)&Ah[(wm * 128 + (m + 4) * 16 + l15) * 32 + swq * 8];
    if (h + 3 < NH) stageB(nslot, h + 3);

    // guard half h+1's Ph1 reads: h+2/h+3 may stay in flight.
    if (h <= 28) {
      asm volatile("s_waitcnt vmcnt(8)" ::: "memory");
    } else if (h == 29) {
      asm volatile("s_waitcnt vmcnt(4)" ::: "memory");
    } else if (h == 30) {
      asm volatile("s_waitcnt vmcnt(0)" ::: "memory");
    }
    __builtin_amdgcn_s_barrier();
    asm volatile("s_waitcnt lgkmcnt(0)" ::: "memory");
    __builtin_amdgcn_s_setprio(1);
#pragma unroll
    for (int m = 0; m < 4; ++m)
#pragma unroll
      for (int n = 0; n < 4; ++n)
        acc[m + 4][n] = __builtin_amdgcn_mfma_f32_16x16x32_bf16(aS[m], bF[n], acc[m + 4][n], 0, 0, 0);
    __builtin_amdgcn_s_setprio(0);
    __builtin_amdgcn_s_barrier();
  }

  // ---- epilogue: dist = xr + xc - 2*G; both-sided masked reductions ----
  __syncthreads();  // repurpose LDS
  float* rowtbl = (float*)smem;            // [4 wn][256 row][3] = 12 KB
  float* coltbl = (float*)(smem + 12288);  // [2 wm][4 wn][4 n][16 l15][3] = 6 KB

  int lc[4]; float xc[4];
#pragma unroll
  for (int n = 0; n < 4; ++n) {
    const int col = colBase + wn * 64 + n * 16 + l15;
    lc[n] = lab[col];
    xc[n] = xn[col];
  }
  float tmax[4], t1[4], t2[4];
#pragma unroll
  for (int n = 0; n < 4; ++n) { tmax[n] = 0.f; t1[n] = kInf; t2[n] = kInf; }

#pragma unroll
  for (int m = 0; m < 8; ++m) {
    int lr4[4]; float xr4[4];
#pragma unroll
    for (int r = 0; r < 4; ++r) {
      const int row = rowBase + wm * 128 + m * 16 + quad * 4 + r;
      lr4[r] = lab[row];
      xr4[r] = xn[row];
    }
    float rmax[4], r1v[4], r2v[4];
#pragma unroll
    for (int r = 0; r < 4; ++r) { rmax[r] = 0.f; r1v[r] = kInf; r2v[r] = kInf; }
#pragma unroll
    for (int n = 0; n < 4; ++n)
#pragma unroll
      for (int r = 0; r < 4; ++r) {
        const float d = fmaf(-2.f, acc[m][n][r], xr4[r] + xc[n]);
        const bool eq = (lr4[r] == lc[n]);
        const bool selfp =
            diag && (wm * 128 + m * 16 + quad * 4 + r) == (wn * 64 + n * 16 + l15);
        const float pos = (eq && !selfp) ? d : 0.f;
        const float dn = eq ? kInf : d;  // self is eq -> excluded from negatives
        rmax[r] = fmaxf(rmax[r], pos);
        min2_insert(r1v[r], r2v[r], dn);
        tmax[n] = fmaxf(tmax[n], pos);
        min2_insert(t1[n], t2[n], dn);
      }
    // merge this m's row stats over the 16 column-lanes (bits 0..3 of lane)
#pragma unroll
    for (int off = 1; off < 16; off <<= 1) {
#pragma unroll
      for (int r = 0; r < 4; ++r) {
        const float om = __shfl_xor(rmax[r], off, 64);
        const float o1 = __shfl_xor(r1v[r], off, 64);
        const float o2 = __shfl_xor(r2v[r], off, 64);
        rmax[r] = fmaxf(rmax[r], om);
        min2_merge(r1v[r], r2v[r], o1, o2);
      }
    }
    if (l15 == 0) {
#pragma unroll
      for (int r = 0; r < 4; ++r) {
        const int row = wm * 128 + m * 16 + quad * 4 + r;
        rowtbl[(wn * 256 + row) * 3 + 0] = rmax[r];
        rowtbl[(wn * 256 + row) * 3 + 1] = r1v[r];
        rowtbl[(wn * 256 + row) * 3 + 2] = r2v[r];
      }
    }
  }

  // merge col stats over the 4 quads (lane bits 4..5)
#pragma unroll
  for (int off = 16; off < 64; off <<= 1) {
#pragma unroll
    for (int n = 0; n < 4; ++n) {
      const float om = __shfl_xor(tmax[n], off, 64);
      const float o1 = __shfl_xor(t1[n], off, 64);
      const float o2 = __shfl_xor(t2[n], off, 64);
      tmax[n] = fmaxf(tmax[n], om);
      min2_merge(t1[n], t2[n], o1, o2);
    }
  }
  if (quad == 0) {
#pragma unroll
    for (int n = 0; n < 4; ++n) {
      const int idx = (((wm * 4 + wn) * 4 + n) * 16 + l15) * 3;
      coltbl[idx + 0] = tmax[n];
      coltbl[idx + 1] = t1[n];
      coltbl[idx + 2] = t2[n];
    }
  }
  __syncthreads();

  if (tid < 256) {
    // row side: merge rowtbl over wn, write P[I][J]
    const int row = tid;
    float M = 0.f, a1 = kInf, a2 = kInf;
#pragma unroll
    for (int w = 0; w < 4; ++w) {
      const int idx = (w * 256 + row) * 3;
      M = fmaxf(M, rowtbl[idx + 0]);
      min2_merge(a1, a2, rowtbl[idx + 1], rowtbl[idx + 2]);
    }
    const size_t p = ((size_t)(I * NB + J)) * 256 + row;
    wsMax[p] = M;
    wsM1[p] = a1;
    wsM2[p] = a2;
  } else if (!diag) {
    // transposed side: merge coltbl over wm, write P[J][I]
    const int x = tid - 256;       // col 0..255
    const int cwn = x >> 6;
    const int cn = (x >> 4) & 3;
    const int cl = x & 15;
    float M = 0.f, a1 = kInf, a2 = kInf;
#pragma unroll
    for (int w = 0; w < 2; ++w) {
      const int idx = (((w * 4 + cwn) * 4 + cn) * 16 + cl) * 3;
      M = fmaxf(M, coltbl[idx + 0]);
      min2_merge(a1, a2, coltbl[idx + 1], coltbl[idx + 2]);
    }
    const size_t p = ((size_t)(J * NB + I)) * 256 + x;
    wsMax[p] = M;
    wsM1[p] = a1;
    wsM2[p] = a2;
  }
}

// ---------------- merge: per-row over 32 col-block partials -> block sums ----
__global__ __launch_bounds__(256) void merge_kernel(
    const float* __restrict__ wsMax, const float* __restrict__ wsM1,
    const float* __restrict__ wsM2, float* __restrict__ bsum,
    float* __restrict__ bcnt) {
  const int r = threadIdx.x;          // 256 rows per block-row, bi == blockIdx.x
  const int bi = blockIdx.x;
  float mp = 0.f, m1 = kInf, m2 = kInf;
#pragma unroll 8
  for (int bj = 0; bj < NB; ++bj) {
    const size_t p = ((size_t)(bi * NB + bj)) * 256 + r;
    mp = fmaxf(mp, wsMax[p]);
    min2_merge(m1, m2, wsM1[p], wsM2[p]);
  }
  const float loss = fmaxf(mp - m2 + kAlpha, 0.f);
  float ls = (loss > kEps) ? loss : 0.f;
  float lc = (loss > kEps) ? 1.f : 0.f;
#pragma unroll
  for (int off = 32; off; off >>= 1) {
    ls += __shfl_down(ls, off, 64);
    lc += __shfl_down(lc, off, 64);
  }
  __shared__ float ss[4], sc[4];
  if ((threadIdx.x & 63) == 0) { ss[threadIdx.x >> 6] = ls; sc[threadIdx.x >> 6] = lc; }
  __syncthreads();
  if (threadIdx.x == 0) {
    bsum[bi] = ss[0] + ss[1] + ss[2] + ss[3];
    bcnt[bi] = sc[0] + sc[1] + sc[2] + sc[3];
  }
}

// ---------------- final: reduce 32 block sums, divide ----------------
__global__ __launch_bounds__(64) void final_kernel(const float* __restrict__ bsum,
                                                   const float* __restrict__ bcnt,
                                                   float* __restrict__ out) {
  float s = (threadIdx.x < NB) ? bsum[threadIdx.x] : 0.f;
  float c = (threadIdx.x < NB) ? bcnt[threadIdx.x] : 0.f;
#pragma unroll
  for (int off = 32; off; off >>= 1) {
    s += __shfl_down(s, off, 64);
    c += __shfl_down(c, off, 64);
  }
  if (threadIdx.x == 0) out[0] = s / c;
}

// ---------------- launch ----------------
extern "C" void kernel_launch(void* const* d_in, const int* in_sizes, int n_in,
                              void* d_out, int out_size, void* d_ws, size_t ws_size,
                              hipStream_t stream) {
  (void)in_sizes; (void)n_in; (void)out_size; (void)ws_size;
  const float* H = (const float*)d_in[0];
  const int* lab = (const int*)d_in[1];
  float* out = (float*)d_out;

  char* ws = (char*)d_ws;
  unsigned short* Hb = (unsigned short*)ws;                              // 16 MB
  float* xn = (float*)(ws + (size_t)Nn * Dd * sizeof(unsigned short));   // 32 KB
  float* wsMax = xn + Nn;                 // 32*32*256 = 256K floats = 1 MB
  float* wsM1 = wsMax + NB * NB * 256;
  float* wsM2 = wsM1 + NB * NB * 256;
  float* bsum = wsM2 + NB * NB * 256;     // 32 floats
  float* bcnt = bsum + NB;

  prep_kernel<<<Nn / 4, 256, 0, stream>>>(H, Hb, xn);
  triplet_main<<<NPAIR, 512, 0, stream>>>(Hb, xn, lab, wsMax, wsM1, wsM2);
  merge_kernel<<<NB, 256, 0, stream>>>(wsMax, wsM1, wsM2, bsum, bcnt);
  final_kernel<<<1, 64, 0, stream>>>(bsum, bcnt, out);
}